// Round 4
// baseline (328.002 us; speedup 1.0000x reference)
//
#include <hip/hip_runtime.h>

// SNN leaky integrate-and-fire, single fused kernel.
// x: [65536, 784] f32, W: [1, 784] f32.
// out = concat(spk_rec [255,65536], mem_rec [255,65536]) f32.
//
// Block = 256 thr (4 waves) owns 64 consecutive rows.
// Phase 1: wave-per-row f64 dot (identical expression + shuffle tree as R2/R3
//          -> bit-identical cur), wave w does rows w*16..w*16+15, unroll-2 for
//          load pipelining. Results to LDS.
// Phase 2: thread i -> (row = i&63, chunk = i>>6); NCHUNK=4 x CHUNK=64
//          time-split with bit-identical fma replay. Wave-uniform warm-up,
//          full 256B coalesced nontemporal stores.
// Single launch: no inter-kernel drain; phase-2 stores of early blocks overlap
// phase-1 reads of later blocks.

#define NROWS   65536
#define DIM     784            // = 196 float4
#define STEPS   255
#define BETA    0.95
#define ROWS_PB 64
#define CHUNK   64             // steps per phase-2 thread (last chunk: 63)
#define NCHUNK  4              // 4*64 - 1 = 255

// one recurrence step; explicit fma pins rounding so every replay is
// bit-identical to the sequential chain
__device__ __forceinline__ double snn_step(double mem, double cur) {
    return (mem > 1.0) ? 0.0 : fma(BETA, mem, cur);
}

__global__ __launch_bounds__(256) void snn_fused(const float* __restrict__ x,
                                                 const float* __restrict__ W,
                                                 float* __restrict__ out) {
    __shared__ double cur_s[ROWS_PB];
    const int tid  = threadIdx.x;
    const int lane = tid & 63;
    const int wave = tid >> 6;                          // 0..3
    const long long rowBase = (long long)blockIdx.x * ROWS_PB;

    // ---- Phase 1: dots for rows wave*16 .. wave*16+15 ----
    {
        const float4* __restrict__ W4 = (const float4*)W;
        const float4 w0 = W4[lane];
        const float4 w1 = W4[lane + 64];
        const float4 w2 = W4[lane + 128];
        float4 w3 = make_float4(0.f, 0.f, 0.f, 0.f);
        if (lane < 4) w3 = W4[192 + lane];

        #pragma unroll 2
        for (int r = 0; r < 16; ++r) {
            const int rl = wave * 16 + r;
            const float4* __restrict__ xr = (const float4*)(x + (rowBase + rl) * DIM);
            float4 a0 = xr[lane];
            float4 a1 = xr[lane + 64];
            float4 a2 = xr[lane + 128];
            float4 a3 = make_float4(0.f, 0.f, 0.f, 0.f);
            if (lane < 4) a3 = xr[192 + lane];

            // EXACT expression from R2/R3 -> bit-identical cur
            double s = (double)a0.x * (double)w0.x + (double)a0.y * (double)w0.y
                     + (double)a0.z * (double)w0.z + (double)a0.w * (double)w0.w
                     + (double)a1.x * (double)w1.x + (double)a1.y * (double)w1.y
                     + (double)a1.z * (double)w1.z + (double)a1.w * (double)w1.w
                     + (double)a2.x * (double)w2.x + (double)a2.y * (double)w2.y
                     + (double)a2.z * (double)w2.z + (double)a2.w * (double)w2.w
                     + (double)a3.x * (double)w3.x + (double)a3.y * (double)w3.y
                     + (double)a3.z * (double)w3.z + (double)a3.w * (double)w3.w;

            #pragma unroll
            for (int off = 32; off > 0; off >>= 1)
                s += __shfl_down(s, off, 64);

            if (lane == 0) cur_s[rl] = s;
        }
    }
    __syncthreads();

    // ---- Phase 2: time-split recurrence ----
    // thread i: row = rowBase + (i & 63), chunk = i >> 6 (wave-uniform)
    const int chunk = wave;
    const long long row = rowBase + lane;
    const double cur = cur_s[lane];
    double mem = 0.0;

    // warm-up: replay steps t = 1 .. 64*chunk (no stores)
    const int warm = CHUNK * chunk;
    #pragma unroll 4
    for (int i = 0; i < warm; ++i)
        mem = snn_step(mem, cur);

    // stored window: steps t = warm+1 .. warm+nst  -> out index t-1
    const int nst = (chunk == NCHUNK - 1) ? (CHUNK - 1) : CHUNK;
    float* __restrict__ spkOut = out + (long long)warm * NROWS + row;
    float* __restrict__ memOut = out + (long long)(STEPS + warm) * NROWS + row;

    for (int i = 0; i < nst; ++i) {
        mem = snn_step(mem, cur);
        __builtin_nontemporal_store((mem > 1.0) ? 1.0f : 0.0f, spkOut);
        __builtin_nontemporal_store((float)mem, memOut);
        spkOut += NROWS;
        memOut += NROWS;
    }
}

extern "C" void kernel_launch(void* const* d_in, const int* in_sizes, int n_in,
                              void* d_out, int out_size, void* d_ws, size_t ws_size,
                              hipStream_t stream) {
    const float* x = (const float*)d_in[0];   // [65536, 784]
    const float* W = (const float*)d_in[1];   // [1, 784]
    float* out = (float*)d_out;               // spk (255*65536) then mem (255*65536)

    hipLaunchKernelGGL(snn_fused, dim3(NROWS / ROWS_PB), dim3(256), 0, stream,
                       x, W, out);
}